// Round 13
// baseline (224.640 us; speedup 1.0000x reference)
//
// ===== MaskedAutoencoderViT v13 — fuse LN2+W_pred into GEMM epilogue =====
// v12: 218.7 µs, top = gemm_w 57.2 µs @ 192 MB traffic (41 MB = Xd write,
// re-read once by pred_w). pred is linear in per-row stats (Σx, Σx², Σu·x)
// -> accumulate them in the GEMM epilogue (shfl_xor 16-lane reduce +
// atomicAdd), drop Xd and pred_w. mask_w computes pred for kept rows.
#include <hip/hip_runtime.h>

typedef __attribute__((ext_vector_type(8))) __bf16 bf16x8;
typedef __attribute__((ext_vector_type(4))) float f32x4;
typedef __attribute__((ext_vector_type(4))) unsigned short us4;

typedef const __attribute__((address_space(1))) void* gas;
typedef __attribute__((address_space(3))) void* las;

static __device__ __forceinline__ unsigned short f2bf(float f) {
  unsigned int u = __float_as_uint(f);
  u += 0x7fffu + ((u >> 16) & 1u);
  return (unsigned short)(u >> 16);
}
static __device__ __forceinline__ float bf2f(unsigned short s) {
  return __uint_as_float(((unsigned int)s) << 16);
}

template <int Q>
__device__ __forceinline__ void btree(float* sm, float* v) {
  const int t = threadIdx.x;
#pragma unroll
  for (int q = 0; q < Q; ++q) sm[q * 256 + t] = v[q];
  __syncthreads();
  for (int o = 128; o > 0; o >>= 1) {
    if (t < o)
#pragma unroll
      for (int q = 0; q < Q; ++q) sm[q * 256 + t] += sm[q * 256 + t + o];
    __syncthreads();
  }
#pragma unroll
  for (int q = 0; q < Q; ++q) v[q] = sm[q * 256];
  __syncthreads();
}

// ---- rank_w: stable-sort rank; thread = (i, j-quarter), 4-way LDS combine ----
__global__ __launch_bounds__(256) void rank_w(const float* __restrict__ noise,
                                              int* __restrict__ rank,
                                              int* __restrict__ keep) {
  __shared__ alignas(16) float nz[2000];
  __shared__ int pc[256];
  const int b = blockIdx.x;
  const int tile = blockIdx.y;
  const int tid = threadIdx.x;
  const float* nr = noise + b * 2000;
  for (int j = tid; j < 500; j += 256)
    ((float4*)nz)[j] = ((const float4*)nr)[j];
  __syncthreads();
  const int il = tid >> 2;
  const int jq = tid & 3;
  const int i = tile * 64 + il;
  int cnt = 0;
  if (i < 2000) {
    const float ni = nz[i];
    const int j0 = jq * 125;
#pragma unroll 5
    for (int j4 = j0; j4 < j0 + 125; ++j4) {
      float4 v = ((const float4*)nz)[j4];
      const int j = j4 * 4;
      cnt += (int)((v.x < ni) | ((v.x == ni) & (j < i)));
      cnt += (int)((v.y < ni) | ((v.y == ni) & ((j + 1) < i)));
      cnt += (int)((v.z < ni) | ((v.z == ni) & ((j + 2) < i)));
      cnt += (int)((v.w < ni) | ((v.w == ni) & ((j + 3) < i)));
    }
  }
  pc[tid] = cnt;
  __syncthreads();
  if (jq == 0 && i < 2000) {
    const int total = pc[tid] + pc[tid + 1] + pc[tid + 2] + pc[tid + 3];
    rank[b * 2000 + i] = total;
    if (total < 500) keep[b * 500 + total] = i;
  }
}

// ---------------- trans_w: W_dec (K x N) -> Bt (N x K) bf16 ----------------
__global__ __launch_bounds__(256) void trans_w(const float* __restrict__ W,
                                               unsigned short* __restrict__ Bt) {
  __shared__ float tile[32][33];
  const int tx = threadIdx.x & 31, ty = threadIdx.x >> 5;
  const int r0 = blockIdx.y * 32, c0 = blockIdx.x * 32;
#pragma unroll
  for (int k = 0; k < 4; ++k)
    tile[ty + k * 8][tx] = W[(size_t)(r0 + ty + k * 8) * 1024 + c0 + tx];
  __syncthreads();
#pragma unroll
  for (int k = 0; k < 4; ++k) {
    const int cr = ty + k * 8;
    Bt[(size_t)(c0 + cr) * 1024 + r0 + tx] = f2bf(tile[tx][cr]);
  }
}

// ------- pre_w: pm = Wp.LN2(mtok)+bp ; u[]=g2*Wp ; scal=[pm, Σu, sc+bp] -------
__global__ __launch_bounds__(256) void pre_w(const float* __restrict__ mtok,
                                             const float* __restrict__ g2,
                                             const float* __restrict__ be2,
                                             const float* __restrict__ Wp,
                                             const float* __restrict__ bp,
                                             float* __restrict__ scal,
                                             float* __restrict__ uw) {
  __shared__ float sm[768];
  const int t = threadIdx.x;
  float4 x = ((const float4*)mtok)[t];
  float v[2];
  v[0] = x.x + x.y + x.z + x.w;
  v[1] = x.x * x.x + x.y * x.y + x.z * x.z + x.w * x.w;
  btree<2>(sm, v);
  const float mean = v[0] * (1.f / 1024.f);
  const float r = rsqrtf(v[1] * (1.f / 1024.f) - mean * mean + 1e-5f);
  float4 g = ((const float4*)g2)[t];
  float4 be = ((const float4*)be2)[t];
  float4 w = ((const float4*)Wp)[t];
  float4 u;
  u.x = g.x * w.x; u.y = g.y * w.y; u.z = g.z * w.z; u.w = g.w * w.w;
  ((float4*)uw)[t] = u;
  float d[3];
  d[0] = ((x.x - mean) * r * g.x + be.x) * w.x +
         ((x.y - mean) * r * g.y + be.y) * w.y +
         ((x.z - mean) * r * g.z + be.z) * w.z +
         ((x.w - mean) * r * g.w + be.w) * w.w;
  d[1] = u.x + u.y + u.z + u.w;
  d[2] = be.x * w.x + be.y * w.y + be.z * w.z + be.w * w.w;
  btree<3>(sm, d);
  if (t == 0) {
    scal[0] = d[0] + bp[0];  // pred for mask-token rows
    scal[1] = d[1];          // Σu
    scal[2] = d[2] + bp[0];  // sc + bp
  }
}

// ------- enc_w: embed + LN1 -> latent (bf16); n==0 -> latent[:,0] (f32 out) -------
__global__ __launch_bounds__(256) void enc_w(
    const float* __restrict__ expr, const int* __restrict__ idx,
    const float* __restrict__ pos, const float* __restrict__ cls,
    const float* __restrict__ wenc, const float* __restrict__ benc,
    const float* __restrict__ g1, const float* __restrict__ be1,
    const int* __restrict__ keep, unsigned short* __restrict__ latent,
    float* __restrict__ out_l0) {
  __shared__ float sm[512];
  const int bx = blockIdx.x;
  const int b = bx / 501, n = bx % 501;
  const int t = threadIdx.x;
  float4 x;
  int m = 0;
  if (n == 0) {
    float4 c = ((const float4*)cls)[t];
    float4 p = ((const float4*)pos)[t];
    x.x = c.x + p.x; x.y = c.y + p.y; x.z = c.z + p.z; x.w = c.w + p.w;
  } else {
    m = b * 500 + n - 1;
    const int i = keep[m];
    const float e = expr[b * 2000 + i];
    const int row = idx[b * 2000 + i];
    float4 w = ((const float4*)wenc)[t];
    float4 bb = ((const float4*)benc)[t];
    float4 p = ((const float4*)(pos + (size_t)row * 1024))[t];
    x.x = fmaf(e, w.x, bb.x) + p.x;
    x.y = fmaf(e, w.y, bb.y) + p.y;
    x.z = fmaf(e, w.z, bb.z) + p.z;
    x.w = fmaf(e, w.w, bb.w) + p.w;
  }
  float v[2];
  v[0] = x.x + x.y + x.z + x.w;
  v[1] = x.x * x.x + x.y * x.y + x.z * x.z + x.w * x.w;
  btree<2>(sm, v);
  const float mean = v[0] * (1.f / 1024.f);
  const float r = rsqrtf(v[1] * (1.f / 1024.f) - mean * mean + 1e-5f);
  float4 g = ((const float4*)g1)[t];
  float4 be = ((const float4*)be1)[t];
  const float y0 = (x.x - mean) * r * g.x + be.x;
  const float y1 = (x.y - mean) * r * g.y + be.y;
  const float y2 = (x.z - mean) * r * g.z + be.z;
  const float y3 = (x.w - mean) * r * g.w + be.w;
  if (n == 0) {
    float* o = out_l0 + b * 1024 + t * 4;  // odd f32 offset: scalar stores
    o[0] = y0; o[1] = y1; o[2] = y2; o[3] = y3;
  } else {
    us4 o; o.x = f2bf(y0); o.y = f2bf(y1); o.z = f2bf(y2); o.w = f2bf(y3);
    ((us4*)(latent + (size_t)m * 1024))[t] = o;
  }
}

// ------- gemm_w: latent @ Bt^T + b_dec -> per-row (Σx, Σx², Σu·x) atomics -------
__global__ __launch_bounds__(256, 3) void gemm_w(
    const unsigned short* __restrict__ A,   // latent [16000][1024] bf16
    const unsigned short* __restrict__ Bt,  // [1024 n][1024 k] bf16
    const float* __restrict__ bdec, const float* __restrict__ uw,
    float* __restrict__ sums) {             // [16000][3]
  __shared__ alignas(16) char lds[16384];
  const int tid = threadIdx.x;
  const int wid = tid >> 6;
  const int lane = tid & 63;
  const int bm = blockIdx.x;  // 125
  const int bn = blockIdx.y;  // 8
  const int wm = wid >> 1, wn = wid & 1;

  const int srow = tid >> 2;
  const int g = (tid & 3) ^ ((tid >> 3) & 3);
  const unsigned short* aS = A + (size_t)(bm * 128 + srow) * 1024 + g * 8;
  const unsigned short* bS = Bt + (size_t)(bn * 128 + srow) * 1024 + g * 8;
  char* ldsA = lds;
  char* ldsB = lds + 8192;
  char* stA = ldsA + wid * 1024;
  char* stB = ldsB + wid * 1024;

  f32x4 acc[4][4];
#pragma unroll
  for (int i = 0; i < 4; ++i)
#pragma unroll
    for (int j = 0; j < 4; ++j) { f32x4 z = {0.f, 0.f, 0.f, 0.f}; acc[i][j] = z; }

  const int r = lane & 15;   // = dc
  const int gg = lane >> 4;  // = dr
  const int swz = ((gg ^ ((r >> 1) & 3)) * 16);
  const int aRd = (wm * 64 + r) * 64 + swz;
  const int bRd = (wn * 64 + r) * 64 + swz;

  for (int ks = 0; ks < 1024; ks += 32) {
    __builtin_amdgcn_global_load_lds((gas)(aS + ks), (las)(stA), 16, 0, 0);
    __builtin_amdgcn_global_load_lds((gas)(aS + 64 * 1024 + ks), (las)(stA + 4096), 16, 0, 0);
    __builtin_amdgcn_global_load_lds((gas)(bS + ks), (las)(stB), 16, 0, 0);
    __builtin_amdgcn_global_load_lds((gas)(bS + 64 * 1024 + ks), (las)(stB + 4096), 16, 0, 0);
    __syncthreads();
    bf16x8 af[4], bfr[4];
#pragma unroll
    for (int mf = 0; mf < 4; ++mf) af[mf] = *(const bf16x8*)(ldsA + aRd + mf * 1024);
#pragma unroll
    for (int nf = 0; nf < 4; ++nf) bfr[nf] = *(const bf16x8*)(ldsB + bRd + nf * 1024);
#pragma unroll
    for (int mf = 0; mf < 4; ++mf)
#pragma unroll
      for (int nf = 0; nf < 4; ++nf)
        acc[mf][nf] = __builtin_amdgcn_mfma_f32_16x16x32_bf16(af[mf], bfr[nf], acc[mf][nf], 0, 0, 0);
    __syncthreads();
  }
  // Epilogue: per-row partial stats over this block's 128 cols.
  const int dc = r, dr = gg;
  float biasv[4], uv[4];
#pragma unroll
  for (int nf = 0; nf < 4; ++nf) {
    const int col = bn * 128 + wn * 64 + nf * 16 + dc;
    biasv[nf] = bdec[col];
    uv[nf] = uw[col];
  }
#pragma unroll
  for (int mf = 0; mf < 4; ++mf) {
#pragma unroll
    for (int q = 0; q < 4; ++q) {
      float s = 0.f, s2 = 0.f, su = 0.f;
#pragma unroll
      for (int nf = 0; nf < 4; ++nf) {
        const float x = acc[mf][nf][q] + biasv[nf];
        s += x; s2 += x * x; su += uv[nf] * x;
      }
#pragma unroll
      for (int msk = 1; msk < 16; msk <<= 1) {  // reduce over dc (16 lanes)
        s += __shfl_xor(s, msk, 64);
        s2 += __shfl_xor(s2, msk, 64);
        su += __shfl_xor(su, msk, 64);
      }
      if (dc == 0) {
        const int row = bm * 128 + wm * 64 + mf * 16 + dr * 4 + q;
        atomicAdd(&sums[row * 3 + 0], s);
        atomicAdd(&sums[row * 3 + 1], s2);
        atomicAdd(&sums[row * 3 + 2], su);
      }
    }
  }
}

// --- mask_w: mask out, pred for masked (pm) AND kept (from sums), loss partials ---
__global__ __launch_bounds__(256) void mask_w(
    const int* __restrict__ rank, const float* __restrict__ expr,
    const float* __restrict__ scal, const float* __restrict__ sums,
    float* __restrict__ out_mask, float* __restrict__ out_pred,
    float* __restrict__ partial) {
  __shared__ float sm[256];
  const int t = blockIdx.x * 256 + threadIdx.x;  // < 64000
  const float pm = scal[0];
  const int rk = rank[t];
  const bool msk = rk >= 500;
  out_mask[t] = msk ? 1.0f : 0.0f;
  float c[1] = {0.f};
  if (msk) {
    out_pred[t] = pm;
    float tv = expr[t];
    if (isnan(tv)) tv = 0.f;
    const float d = pm - tv;
    c[0] = d * d;
  } else {
    const int m = (t / 2000) * 500 + rk;  // dense GEMM row for this kept token
    const float s = sums[m * 3 + 0];
    const float s2 = sums[m * 3 + 1];
    const float su = sums[m * 3 + 2];
    const float mean = s * (1.f / 1024.f);
    const float rr = rsqrtf(s2 * (1.f / 1024.f) - mean * mean + 1e-5f);
    out_pred[t] = rr * (su - mean * scal[1]) + scal[2];
  }
  btree<1>(sm, c);
  if (threadIdx.x == 0) partial[blockIdx.x] = c[0];
}

// ------- fin_w: deterministic final loss over 250 partials (f32 out) -------
__global__ __launch_bounds__(256) void fin_w(const float* __restrict__ partial,
                                             float* __restrict__ out) {
  __shared__ float sm[256];
  const int t = threadIdx.x;
  float v[1];
  v[0] = (t < 250) ? partial[t] : 0.f;
  btree<1>(sm, v);
  if (t == 0) out[0] = v[0] * (1.f / 48000.f);
}

extern "C" void kernel_launch(void* const* d_in, const int* in_sizes, int n_in,
                              void* d_out, int out_size, void* d_ws, size_t ws_size,
                              hipStream_t stream) {
  const float* expr = (const float*)d_in[0];
  const int* idx = (const int*)d_in[1];
  const float* noise = (const float*)d_in[2];
  const float* pos = (const float*)d_in[3];
  const float* cls = (const float*)d_in[4];
  const float* wenc = (const float*)d_in[5];
  const float* benc = (const float*)d_in[6];
  const float* g1 = (const float*)d_in[7];
  const float* be1 = (const float*)d_in[8];
  const float* Wdec = (const float*)d_in[9];
  const float* bdec = (const float*)d_in[10];
  const float* mtok = (const float*)d_in[11];
  const float* g2 = (const float*)d_in[12];
  const float* be2 = (const float*)d_in[13];
  const float* Wp = (const float*)d_in[14];
  const float* bp = (const float*)d_in[15];
  float* out = (float*)d_out;

  char* ws = (char*)d_ws;
  int* rank = (int*)ws;                                   // 256000 B
  int* keep = (int*)(ws + 256000);                        // 64000 B
  float* scal = (float*)(ws + 320000);                    // 64 B
  float* partial = (float*)(ws + 320064);                 // 1024 B
  float* uw = (float*)(ws + 321088);                      // 4096 B
  unsigned short* Bt = (unsigned short*)(ws + 325184);    // 2 MB
  unsigned short* latent = (unsigned short*)(ws + 325184 + 2097152);  // 32 MB
  float* sums = (float*)(ws + 325184 + 2097152 + 32768000);           // 192000 B
  if (ws_size < (size_t)(325184 + 2097152 + 32768000 + 192000)) return;

  float* out_pred = out + 1;
  float* out_mask = out + 64001;
  float* out_l0 = out + 128001;

  hipMemsetAsync(sums, 0, 16000 * 3 * sizeof(float), stream);
  rank_w<<<dim3(32, 32), 256, 0, stream>>>(noise, rank, keep);
  trans_w<<<dim3(32, 32), 256, 0, stream>>>(Wdec, Bt);
  pre_w<<<1, 256, 0, stream>>>(mtok, g2, be2, Wp, bp, scal, uw);
  enc_w<<<32 * 501, 256, 0, stream>>>(expr, idx, pos, cls, wenc, benc, g1, be1,
                                      keep, latent, out_l0);
  gemm_w<<<dim3(125, 8), 256, 0, stream>>>(latent, Bt, bdec, uw, sums);
  mask_w<<<250, 256, 0, stream>>>(rank, expr, scal, sums, out_mask, out_pred,
                                  partial);
  fin_w<<<1, 256, 0, stream>>>(partial, out);
}

// Round 15
// 197.831 us; speedup vs baseline: 1.1355x; 1.1355x over previous
//
// ===== MaskedAutoencoderViT v15 — fix sums race (wn co-writer) =====
// v14: loss passed, pred failed 1.875 -> kept-row sums wrong. Root cause:
// two waves (wn=0,1) share each row's 128 cols and raced on sums[row][bn].
// Fix: sums[16000][16][3], slot bn*2+wn (true single writer); mask_w
// reduces 16 partials.
#include <hip/hip_runtime.h>

typedef __attribute__((ext_vector_type(8))) __bf16 bf16x8;
typedef __attribute__((ext_vector_type(4))) float f32x4;
typedef __attribute__((ext_vector_type(4))) unsigned short us4;

typedef const __attribute__((address_space(1))) void* gas;
typedef __attribute__((address_space(3))) void* las;

static __device__ __forceinline__ unsigned short f2bf(float f) {
  unsigned int u = __float_as_uint(f);
  u += 0x7fffu + ((u >> 16) & 1u);
  return (unsigned short)(u >> 16);
}
static __device__ __forceinline__ float bf2f(unsigned short s) {
  return __uint_as_float(((unsigned int)s) << 16);
}

template <int Q>
__device__ __forceinline__ void btree(float* sm, float* v) {
  const int t = threadIdx.x;
#pragma unroll
  for (int q = 0; q < Q; ++q) sm[q * 256 + t] = v[q];
  __syncthreads();
  for (int o = 128; o > 0; o >>= 1) {
    if (t < o)
#pragma unroll
      for (int q = 0; q < Q; ++q) sm[q * 256 + t] += sm[q * 256 + t + o];
    __syncthreads();
  }
#pragma unroll
  for (int q = 0; q < Q; ++q) v[q] = sm[q * 256];
  __syncthreads();
}

// ---- rank_w: stable-sort rank; thread = (i, j-quarter), 4-way LDS combine ----
__global__ __launch_bounds__(256) void rank_w(const float* __restrict__ noise,
                                              int* __restrict__ rank,
                                              int* __restrict__ keep) {
  __shared__ alignas(16) float nz[2000];
  __shared__ int pc[256];
  const int b = blockIdx.x;
  const int tile = blockIdx.y;
  const int tid = threadIdx.x;
  const float* nr = noise + b * 2000;
  for (int j = tid; j < 500; j += 256)
    ((float4*)nz)[j] = ((const float4*)nr)[j];
  __syncthreads();
  const int il = tid >> 2;
  const int jq = tid & 3;
  const int i = tile * 64 + il;
  int cnt = 0;
  if (i < 2000) {
    const float ni = nz[i];
    const int j0 = jq * 125;
#pragma unroll 5
    for (int j4 = j0; j4 < j0 + 125; ++j4) {
      float4 v = ((const float4*)nz)[j4];
      const int j = j4 * 4;
      cnt += (int)((v.x < ni) | ((v.x == ni) & (j < i)));
      cnt += (int)((v.y < ni) | ((v.y == ni) & ((j + 1) < i)));
      cnt += (int)((v.z < ni) | ((v.z == ni) & ((j + 2) < i)));
      cnt += (int)((v.w < ni) | ((v.w == ni) & ((j + 3) < i)));
    }
  }
  pc[tid] = cnt;
  __syncthreads();
  if (jq == 0 && i < 2000) {
    const int total = pc[tid] + pc[tid + 1] + pc[tid + 2] + pc[tid + 3];
    rank[b * 2000 + i] = total;
    if (total < 500) keep[b * 500 + total] = i;
  }
}

// ---------------- trans_w: W_dec (K x N) -> Bt (N x K) bf16 ----------------
__global__ __launch_bounds__(256) void trans_w(const float* __restrict__ W,
                                               unsigned short* __restrict__ Bt) {
  __shared__ float tile[32][33];
  const int tx = threadIdx.x & 31, ty = threadIdx.x >> 5;
  const int r0 = blockIdx.y * 32, c0 = blockIdx.x * 32;
#pragma unroll
  for (int k = 0; k < 4; ++k)
    tile[ty + k * 8][tx] = W[(size_t)(r0 + ty + k * 8) * 1024 + c0 + tx];
  __syncthreads();
#pragma unroll
  for (int k = 0; k < 4; ++k) {
    const int cr = ty + k * 8;
    Bt[(size_t)(c0 + cr) * 1024 + r0 + tx] = f2bf(tile[tx][cr]);
  }
}

// ------- pre_w: pm = Wp.LN2(mtok)+bp ; u[]=g2*Wp ; scal=[pm, Σu, sc+bp] -------
__global__ __launch_bounds__(256) void pre_w(const float* __restrict__ mtok,
                                             const float* __restrict__ g2,
                                             const float* __restrict__ be2,
                                             const float* __restrict__ Wp,
                                             const float* __restrict__ bp,
                                             float* __restrict__ scal,
                                             float* __restrict__ uw) {
  __shared__ float sm[768];
  const int t = threadIdx.x;
  float4 x = ((const float4*)mtok)[t];
  float v[2];
  v[0] = x.x + x.y + x.z + x.w;
  v[1] = x.x * x.x + x.y * x.y + x.z * x.z + x.w * x.w;
  btree<2>(sm, v);
  const float mean = v[0] * (1.f / 1024.f);
  const float r = rsqrtf(v[1] * (1.f / 1024.f) - mean * mean + 1e-5f);
  float4 g = ((const float4*)g2)[t];
  float4 be = ((const float4*)be2)[t];
  float4 w = ((const float4*)Wp)[t];
  float4 u;
  u.x = g.x * w.x; u.y = g.y * w.y; u.z = g.z * w.z; u.w = g.w * w.w;
  ((float4*)uw)[t] = u;
  float d[3];
  d[0] = ((x.x - mean) * r * g.x + be.x) * w.x +
         ((x.y - mean) * r * g.y + be.y) * w.y +
         ((x.z - mean) * r * g.z + be.z) * w.z +
         ((x.w - mean) * r * g.w + be.w) * w.w;
  d[1] = u.x + u.y + u.z + u.w;
  d[2] = be.x * w.x + be.y * w.y + be.z * w.z + be.w * w.w;
  btree<3>(sm, d);
  if (t == 0) {
    scal[0] = d[0] + bp[0];  // pred for mask-token rows
    scal[1] = d[1];          // Σu
    scal[2] = d[2] + bp[0];  // sc + bp
  }
}

// ------- enc_w: embed + LN1 -> latent (bf16); n==0 -> latent[:,0] (f32 out) -------
__global__ __launch_bounds__(256) void enc_w(
    const float* __restrict__ expr, const int* __restrict__ idx,
    const float* __restrict__ pos, const float* __restrict__ cls,
    const float* __restrict__ wenc, const float* __restrict__ benc,
    const float* __restrict__ g1, const float* __restrict__ be1,
    const int* __restrict__ keep, unsigned short* __restrict__ latent,
    float* __restrict__ out_l0) {
  __shared__ float sm[512];
  const int bx = blockIdx.x;
  const int b = bx / 501, n = bx % 501;
  const int t = threadIdx.x;
  float4 x;
  int m = 0;
  if (n == 0) {
    float4 c = ((const float4*)cls)[t];
    float4 p = ((const float4*)pos)[t];
    x.x = c.x + p.x; x.y = c.y + p.y; x.z = c.z + p.z; x.w = c.w + p.w;
  } else {
    m = b * 500 + n - 1;
    const int i = keep[m];
    const float e = expr[b * 2000 + i];
    const int row = idx[b * 2000 + i];
    float4 w = ((const float4*)wenc)[t];
    float4 bb = ((const float4*)benc)[t];
    float4 p = ((const float4*)(pos + (size_t)row * 1024))[t];
    x.x = fmaf(e, w.x, bb.x) + p.x;
    x.y = fmaf(e, w.y, bb.y) + p.y;
    x.z = fmaf(e, w.z, bb.z) + p.z;
    x.w = fmaf(e, w.w, bb.w) + p.w;
  }
  float v[2];
  v[0] = x.x + x.y + x.z + x.w;
  v[1] = x.x * x.x + x.y * x.y + x.z * x.z + x.w * x.w;
  btree<2>(sm, v);
  const float mean = v[0] * (1.f / 1024.f);
  const float r = rsqrtf(v[1] * (1.f / 1024.f) - mean * mean + 1e-5f);
  float4 g = ((const float4*)g1)[t];
  float4 be = ((const float4*)be1)[t];
  const float y0 = (x.x - mean) * r * g.x + be.x;
  const float y1 = (x.y - mean) * r * g.y + be.y;
  const float y2 = (x.z - mean) * r * g.z + be.z;
  const float y3 = (x.w - mean) * r * g.w + be.w;
  if (n == 0) {
    float* o = out_l0 + b * 1024 + t * 4;  // odd f32 offset: scalar stores
    o[0] = y0; o[1] = y1; o[2] = y2; o[3] = y3;
  } else {
    us4 o; o.x = f2bf(y0); o.y = f2bf(y1); o.z = f2bf(y2); o.w = f2bf(y3);
    ((us4*)(latent + (size_t)m * 1024))[t] = o;
  }
}

// --- gemm_w: latent @ Bt^T + b_dec -> per-(row,bn,wn) stats, plain stores ---
__global__ __launch_bounds__(256, 3) void gemm_w(
    const unsigned short* __restrict__ A,   // latent [16000][1024] bf16
    const unsigned short* __restrict__ Bt,  // [1024 n][1024 k] bf16
    const float* __restrict__ bdec, const float* __restrict__ uw,
    float* __restrict__ sums) {             // [16000][16][3]
  __shared__ alignas(16) char lds[16384];
  const int tid = threadIdx.x;
  const int wid = tid >> 6;
  const int lane = tid & 63;
  const int bn = blockIdx.x;  // 8  (fast: consecutive blocks share A-tile)
  const int bm = blockIdx.y;  // 125
  const int wm = wid >> 1, wn = wid & 1;

  const int srow = tid >> 2;
  const int g = (tid & 3) ^ ((tid >> 3) & 3);
  const unsigned short* aS = A + (size_t)(bm * 128 + srow) * 1024 + g * 8;
  const unsigned short* bS = Bt + (size_t)(bn * 128 + srow) * 1024 + g * 8;
  char* ldsA = lds;
  char* ldsB = lds + 8192;
  char* stA = ldsA + wid * 1024;
  char* stB = ldsB + wid * 1024;

  f32x4 acc[4][4];
#pragma unroll
  for (int i = 0; i < 4; ++i)
#pragma unroll
    for (int j = 0; j < 4; ++j) { f32x4 z = {0.f, 0.f, 0.f, 0.f}; acc[i][j] = z; }

  const int r = lane & 15;   // = dc
  const int gg = lane >> 4;  // = dr
  const int swz = ((gg ^ ((r >> 1) & 3)) * 16);
  const int aRd = (wm * 64 + r) * 64 + swz;
  const int bRd = (wn * 64 + r) * 64 + swz;

  for (int ks = 0; ks < 1024; ks += 32) {
    __builtin_amdgcn_global_load_lds((gas)(aS + ks), (las)(stA), 16, 0, 0);
    __builtin_amdgcn_global_load_lds((gas)(aS + 64 * 1024 + ks), (las)(stA + 4096), 16, 0, 0);
    __builtin_amdgcn_global_load_lds((gas)(bS + ks), (las)(stB), 16, 0, 0);
    __builtin_amdgcn_global_load_lds((gas)(bS + 64 * 1024 + ks), (las)(stB + 4096), 16, 0, 0);
    __syncthreads();
    bf16x8 af[4], bfr[4];
#pragma unroll
    for (int mf = 0; mf < 4; ++mf) af[mf] = *(const bf16x8*)(ldsA + aRd + mf * 1024);
#pragma unroll
    for (int nf = 0; nf < 4; ++nf) bfr[nf] = *(const bf16x8*)(ldsB + bRd + nf * 1024);
#pragma unroll
    for (int mf = 0; mf < 4; ++mf)
#pragma unroll
      for (int nf = 0; nf < 4; ++nf)
        acc[mf][nf] = __builtin_amdgcn_mfma_f32_16x16x32_bf16(af[mf], bfr[nf], acc[mf][nf], 0, 0, 0);
    __syncthreads();
  }
  // Epilogue: per-row partial stats over THIS WAVE's 64 cols; slot indexed
  // by (bn, wn) -> genuinely one writer per slot, plain stores, no init.
  const int dc = r, dr = gg;
  float biasv[4], uv[4];
#pragma unroll
  for (int nf = 0; nf < 4; ++nf) {
    const int col = bn * 128 + wn * 64 + nf * 16 + dc;
    biasv[nf] = bdec[col];
    uv[nf] = uw[col];
  }
#pragma unroll
  for (int mf = 0; mf < 4; ++mf) {
#pragma unroll
    for (int q = 0; q < 4; ++q) {
      float s = 0.f, s2 = 0.f, su = 0.f;
#pragma unroll
      for (int nf = 0; nf < 4; ++nf) {
        const float x = acc[mf][nf][q] + biasv[nf];
        s += x; s2 += x * x; su += uv[nf] * x;
      }
#pragma unroll
      for (int msk = 1; msk < 16; msk <<= 1) {  // reduce over dc (16 lanes)
        s += __shfl_xor(s, msk, 64);
        s2 += __shfl_xor(s2, msk, 64);
        su += __shfl_xor(su, msk, 64);
      }
      if (dc == 0) {
        const int row = bm * 128 + wm * 64 + mf * 16 + dr * 4 + q;
        float* p = &sums[((size_t)row * 16 + bn * 2 + wn) * 3];
        p[0] = s; p[1] = s2; p[2] = su;
      }
    }
  }
}

// --- mask_w: mask out, pred for masked (pm) AND kept (reduce 16 partials) ---
__global__ __launch_bounds__(256) void mask_w(
    const int* __restrict__ rank, const float* __restrict__ expr,
    const float* __restrict__ scal, const float* __restrict__ sums,
    float* __restrict__ out_mask, float* __restrict__ out_pred,
    float* __restrict__ partial) {
  __shared__ float sm[256];
  const int t = blockIdx.x * 256 + threadIdx.x;  // < 64000
  const float pm = scal[0];
  const int rk = rank[t];
  const bool msk = rk >= 500;
  out_mask[t] = msk ? 1.0f : 0.0f;
  float c[1] = {0.f};
  if (msk) {
    out_pred[t] = pm;
    float tv = expr[t];
    if (isnan(tv)) tv = 0.f;
    const float d = pm - tv;
    c[0] = d * d;
  } else {
    const int m = (t / 2000) * 500 + rk;  // dense GEMM row for this kept token
    const float* p = &sums[(size_t)m * 48];
    float s = 0.f, s2 = 0.f, su = 0.f;
#pragma unroll
    for (int k = 0; k < 16; ++k) {
      s += p[k * 3 + 0]; s2 += p[k * 3 + 1]; su += p[k * 3 + 2];
    }
    const float mean = s * (1.f / 1024.f);
    const float rr = rsqrtf(s2 * (1.f / 1024.f) - mean * mean + 1e-5f);
    out_pred[t] = rr * (su - mean * scal[1]) + scal[2];
  }
  btree<1>(sm, c);
  if (threadIdx.x == 0) partial[blockIdx.x] = c[0];
}

// ------- fin_w: deterministic final loss over 250 partials (f32 out) -------
__global__ __launch_bounds__(256) void fin_w(const float* __restrict__ partial,
                                             float* __restrict__ out) {
  __shared__ float sm[256];
  const int t = threadIdx.x;
  float v[1];
  v[0] = (t < 250) ? partial[t] : 0.f;
  btree<1>(sm, v);
  if (t == 0) out[0] = v[0] * (1.f / 48000.f);
}

extern "C" void kernel_launch(void* const* d_in, const int* in_sizes, int n_in,
                              void* d_out, int out_size, void* d_ws, size_t ws_size,
                              hipStream_t stream) {
  const float* expr = (const float*)d_in[0];
  const int* idx = (const int*)d_in[1];
  const float* noise = (const float*)d_in[2];
  const float* pos = (const float*)d_in[3];
  const float* cls = (const float*)d_in[4];
  const float* wenc = (const float*)d_in[5];
  const float* benc = (const float*)d_in[6];
  const float* g1 = (const float*)d_in[7];
  const float* be1 = (const float*)d_in[8];
  const float* Wdec = (const float*)d_in[9];
  const float* bdec = (const float*)d_in[10];
  const float* mtok = (const float*)d_in[11];
  const float* g2 = (const float*)d_in[12];
  const float* be2 = (const float*)d_in[13];
  const float* Wp = (const float*)d_in[14];
  const float* bp = (const float*)d_in[15];
  float* out = (float*)d_out;

  char* ws = (char*)d_ws;
  int* rank = (int*)ws;                                   // 256000 B
  int* keep = (int*)(ws + 256000);                        // 64000 B
  float* scal = (float*)(ws + 320000);                    // 64 B
  float* partial = (float*)(ws + 320064);                 // 1024 B
  float* uw = (float*)(ws + 321088);                      // 4096 B
  unsigned short* Bt = (unsigned short*)(ws + 325184);    // 2 MB
  unsigned short* latent = (unsigned short*)(ws + 325184 + 2097152);  // 32 MB
  float* sums = (float*)(ws + 325184 + 2097152 + 32768000);  // 16000*16*3*4 B
  if (ws_size < (size_t)(325184 + 2097152 + 32768000 + 3072000)) return;

  float* out_pred = out + 1;
  float* out_mask = out + 64001;
  float* out_l0 = out + 128001;

  rank_w<<<dim3(32, 32), 256, 0, stream>>>(noise, rank, keep);
  trans_w<<<dim3(32, 32), 256, 0, stream>>>(Wdec, Bt);
  pre_w<<<1, 256, 0, stream>>>(mtok, g2, be2, Wp, bp, scal, uw);
  enc_w<<<32 * 501, 256, 0, stream>>>(expr, idx, pos, cls, wenc, benc, g1, be1,
                                      keep, latent, out_l0);
  gemm_w<<<dim3(8, 125), 256, 0, stream>>>(latent, Bt, bdec, uw, sums);
  mask_w<<<250, 256, 0, stream>>>(rank, expr, scal, sums, out_mask, out_pred,
                                  partial);
  fin_w<<<1, 256, 0, stream>>>(partial, out);
}